// Round 3
// baseline (278.211 us; speedup 1.0000x reference)
//
#include <hip/hip_runtime.h>
#include <hip/hip_bf16.h>

typedef unsigned short u16;
typedef unsigned int u32;
typedef __attribute__((ext_vector_type(8))) short bf16x8;
typedef __attribute__((ext_vector_type(4))) float f32x4;

#define T_DIM 2048
#define B_DIM 32
#define H_DIM 512

__device__ inline unsigned pack2(float a, float b) {
  union { __hip_bfloat162 h2; unsigned u; } c;
  c.h2 = __float22bfloat162_rn(make_float2(a, b));
  return c.u;
}

// Direct HBM->LDS staging, no VGPR round-trip. Size must be literal 16.
__device__ __forceinline__ void gld16(const void* g, void* s) {
  __builtin_amdgcn_global_load_lds(
      (const __attribute__((address_space(1))) void*)g,
      (__attribute__((address_space(3))) void*)s, 16, 0, 0);
}

// Precompute: r[b*512+h] = hidden[b]·W1[h] + b_attn[h]; u[h] = W3[h]·W_cov;
// W2bf = bf16(W2) in FRAGMENT-MAJOR layout (unchanged, harness-verified).
__global__ __launch_bounds__(256) void prep_kernel(
    const float* __restrict__ hidden, const float* __restrict__ W_attn,
    const float* __restrict__ b_attn, const float* __restrict__ W_cov,
    u16* __restrict__ W2bf, float* __restrict__ r, float* __restrict__ u)
{
  const int tid = blockIdx.x * 256 + threadIdx.x;  // 0..65535
  const int pair = tid >> 2;                       // b*512 + h
  const int kq = tid & 3;
  const int b = pair >> 9, h = pair & 511;

  {
    const float* hid = hidden + b * 512 + kq * 128;
    const float* w1 = W_attn + (size_t)h * 1536 + kq * 128;
    float acc = 0.f;
    #pragma unroll 8
    for (int k = 0; k < 128; k += 4) {
      float4 x = *(const float4*)(hid + k);
      float4 w = *(const float4*)(w1 + k);
      acc += x.x * w.x + x.y * w.y + x.z * w.z + x.w * w.w;
    }
    acc += __shfl_xor(acc, 1);
    acc += __shfl_xor(acc, 2);
    if (kq == 0) r[pair] = acc + b_attn[h];
  }

  {
    int j0 = tid * 4;
    int hh = j0 >> 9, kk = j0 & 511;
    float4 w = *(const float4*)(W_attn + (size_t)hh * 1536 + 512 + kk);
    uint2 p;
    p.x = pack2(w.x, w.y);
    p.y = pack2(w.z, w.w);
    int f = hh >> 4, c = hh & 15;
    int ks = kk >> 5, quad = (kk >> 3) & 3, e = kk & 7;   // e in {0,4}
    *(uint2*)(W2bf + (size_t)((f * 16 + ks) * 64 + quad * 16 + c) * 8 + e) = p;
  }

  if (tid < 2048) {
    int h3 = tid >> 2;
    const float* w3 = W_attn + (size_t)h3 * 1536 + 1024 + kq * 128;
    const float* wc = W_cov + kq * 128;
    float su = 0.f;
    #pragma unroll 8
    for (int k = 0; k < 128; k += 4) {
      float4 a = *(const float4*)(w3 + k);
      float4 c = *(const float4*)(wc + k);
      su += a.x * c.x + a.y * c.y + a.z * c.z + a.w * c.w;
    }
    su += __shfl_xor(su, 1);
    su += __shfl_xor(su, 2);
    if (kq == 0) u[h3] = su;
  }
}

// v4: one block (1024 thr, 16 waves as 2 wr x 8 wc) per 64-row tile (t = 2*tile,
// 2*tile+1). A tile K-split into 4 chunks of 128 floats; LDS = 2 x 32KB fp32
// double buffer. Pipeline: stage chunk kc+1 (gld16, zero VGPRs) at top of chunk
// kc's compute; one barrier per chunk -> HBM streams under compute instead of
// stop-start phases. B frags from fragment-major W2bf, register double-buffered.
// __launch_bounds__(1024,4) caps VGPR at 128 so the full 16-wave block is resident.
__global__ __launch_bounds__(1024, 4) void gemm_score(
    const float* __restrict__ enc, const u16* __restrict__ W2bf,
    const float* __restrict__ r, const float* __restrict__ u,
    const float* __restrict__ vv, const float* __restrict__ cov,
    float* __restrict__ part)
{
  const int tile = blockIdx.x;         // rows m0..m0+63; t = tile*2 + {0,1}
  const int m0 = tile * 64;
  const int tid = threadIdx.x;
  const int lane = tid & 63;
  const int w = tid >> 6;              // 0..15
  const int wr = w >> 3;               // 0..1: rows [wr*32, wr*32+32)
  const int wc = w & 7;                // 0..7: n-slab [wc*64, wc*64+64)
  const int quad = lane >> 4, col = lane & 15;

  __shared__ float As[2][64 * 128];    // 2 x 32 KB, [row][kchunk], 16B-granule XOR swizzle

  // ---- B: initial loads for ks=0,1 (in flight during stage+barrier) ----
  const u16* bbase = W2bf + (size_t)wc * 32768 + lane * 8;
  bf16x8 bb[2][4];
  #pragma unroll
  for (int j = 0; j < 4; ++j) {
    bb[0][j] = *(const bf16x8*)(bbase + j * 8192);
    bb[1][j] = *(const bf16x8*)(bbase + j * 8192 + 512);
  }

  // ---- Stage chunk 0 ----
  {
    #pragma unroll
    for (int q = 0; q < 2; ++q) {
      int n = w * 2 + q;                        // KB-unit 0..31 (rows 2n, 2n+1)
      int rr = n * 2 + (lane >> 5);
      int gl = lane & 31;
      int gsrc = gl ^ (rr & 7);                 // source-side swizzle (rule 21)
      gld16(enc + (size_t)(m0 + rr) * 512 + gsrc * 4, (void*)(&As[0][n * 256]));
    }
  }
  __syncthreads();

  f32x4 acc[2][4] = {};
  const int o0 = (((quad * 2)    ) ^ (col & 7)) * 4;   // swizzled float offsets
  const int o1 = (((quad * 2) + 1) ^ (col & 7)) * 4;

  float4 areg[2][2][2];   // [ksl parity][i][p]

  #pragma unroll
  for (int kc = 0; kc < 4; ++kc) {
    // stage chunk kc+1 into the other buffer (prev barrier freed it)
    if (kc < 3) {
      #pragma unroll
      for (int q = 0; q < 2; ++q) {
        int n = w * 2 + q;
        int rr = n * 2 + (lane >> 5);
        int gl = lane & 31;
        int gsrc = gl ^ (rr & 7);
        gld16(enc + (size_t)(m0 + rr) * 512 + (kc + 1) * 128 + gsrc * 4,
              (void*)(&As[(kc + 1) & 1][n * 256]));
      }
    }
    const float* abase = &As[kc & 1][0];
    // preload ksl=0 A-frags
    #pragma unroll
    for (int i = 0; i < 2; ++i) {
      const float* ap = abase + (wr * 32 + i * 16 + col) * 128;
      areg[0][i][0] = *(const float4*)(ap + o0);
      areg[0][i][1] = *(const float4*)(ap + o1);
    }
    #pragma unroll
    for (int ksl = 0; ksl < 4; ++ksl) {
      const int ks = kc * 4 + ksl;              // global K-step 0..15
      if (ksl < 3) {                            // A prefetch for ksl+1
        #pragma unroll
        for (int i = 0; i < 2; ++i) {
          const float* ap = abase + (wr * 32 + i * 16 + col) * 128 + (ksl + 1) * 32;
          areg[(ksl + 1) & 1][i][0] = *(const float4*)(ap + o0);
          areg[(ksl + 1) & 1][i][1] = *(const float4*)(ap + o1);
        }
      }
      #pragma unroll
      for (int i = 0; i < 2; ++i) {
        float4 f0 = areg[ksl & 1][i][0];
        float4 f1 = areg[ksl & 1][i][1];
        union { bf16x8 v; u32 uu[4]; } af;
        af.uu[0] = pack2(f0.x, f0.y);
        af.uu[1] = pack2(f0.z, f0.w);
        af.uu[2] = pack2(f1.x, f1.y);
        af.uu[3] = pack2(f1.z, f1.w);
        #pragma unroll
        for (int j = 0; j < 4; ++j)
          acc[i][j] = __builtin_amdgcn_mfma_f32_16x16x32_bf16(af.v, bb[ks & 1][j], acc[i][j], 0, 0, 0);
      }
      if (ks < 14) {                            // B prefetch for ks+2
        #pragma unroll
        for (int j = 0; j < 4; ++j)
          bb[ks & 1][j] = *(const bf16x8*)(bbase + j * 8192 + (ks + 2) * 512);
      }
    }
    __syncthreads();   // chunk kc reads done; chunk kc+1 staged (vmcnt drained)
  }

  // ---- Epilogue: e = relu(acc + r[b,h] + cov[b,t]*u[h]); partial = e·v;
  //      wave-level col reduce, then cross-wave LDS reduce (As dead) ----
  float uj[4], vj[4];
  #pragma unroll
  for (int j = 0; j < 4; ++j) {
    int gh = wc * 64 + j * 16 + col;
    uj[j] = u[gh];
    vj[j] = vv[gh];
  }
  float* red = &As[0][0];              // red[row_local * 8 + wc], 512 floats

  #pragma unroll
  for (int i = 0; i < 2; ++i) {
    #pragma unroll
    for (int reg = 0; reg < 4; ++reg) {
      int bl = i * 16 + quad * 4 + reg;          // 0..31
      int rl = wr * 32 + bl;                     // row_local 0..63
      int t = tile * 2 + wr;
      float cv = cov[bl * 2048 + t];
      float s = 0.f;
      #pragma unroll
      for (int j = 0; j < 4; ++j) {
        float rv = r[bl * 512 + wc * 64 + j * 16 + col];
        float e = acc[i][j][reg] + rv + cv * uj[j];
        e = fmaxf(e, 0.f);
        s += e * vj[j];
      }
      s += __shfl_xor(s, 1);
      s += __shfl_xor(s, 2);
      s += __shfl_xor(s, 4);
      s += __shfl_xor(s, 8);
      if (col == 0) red[rl * 8 + wc] = s;
    }
  }
  __syncthreads();
  if (tid < 64) {
    float s = 0.f;
    #pragma unroll
    for (int p = 0; p < 8; ++p) s += red[tid * 8 + p];
    int t = tile * 2 + (tid >> 5), bl = tid & 31;
    part[(size_t)bl * 2048 + t] = s;             // final score[b][t]
  }
}

// Softmax over T per batch + coverage update. 32 blocks x 256 threads.
__global__ __launch_bounds__(256) void softmax_kernel(
    const float* __restrict__ part, const float* __restrict__ cov, float* __restrict__ out)
{
  const int b = blockIdx.x;
  const int tid = threadIdx.x;
  const int lane = tid & 63, wid = tid >> 6;
  __shared__ float red[4];
  float loc[8];
  float lmax = -3.4e38f;
  #pragma unroll
  for (int i = 0; i < 8; ++i) {
    int t = tid + i * 256;
    float s = part[(size_t)b * 2048 + t];
    loc[i] = s;
    lmax = fmaxf(lmax, s);
  }
  #pragma unroll
  for (int o = 32; o; o >>= 1) lmax = fmaxf(lmax, __shfl_xor(lmax, o));
  if (lane == 0) red[wid] = lmax;
  __syncthreads();
  float bmax = fmaxf(fmaxf(red[0], red[1]), fmaxf(red[2], red[3]));
  __syncthreads();
  float lsum = 0.f;
  #pragma unroll
  for (int i = 0; i < 8; ++i) { loc[i] = __expf(loc[i] - bmax); lsum += loc[i]; }
  #pragma unroll
  for (int o = 32; o; o >>= 1) lsum += __shfl_xor(lsum, o);
  if (lane == 0) red[wid] = lsum;
  __syncthreads();
  float inv = 1.0f / (red[0] + red[1] + red[2] + red[3]);
  #pragma unroll
  for (int i = 0; i < 8; ++i) {
    int t = tid + i * 256;
    float a = loc[i] * inv;
    out[b * 2048 + t] = a;                               // attn_weights [B,1,T]
    out[65536 + b * 2048 + t] = cov[b * 2048 + t] + a;   // coverage_new [B,T]
  }
}

extern "C" void kernel_launch(void* const* d_in, const int* in_sizes, int n_in,
                              void* d_out, int out_size, void* d_ws, size_t ws_size,
                              hipStream_t stream) {
  const float* hidden = (const float*)d_in[0];   // [1,B,H]
  const float* enc    = (const float*)d_in[1];   // [T,B,H]
  const float* cov    = (const float*)d_in[2];   // [B,T]
  const float* W_attn = (const float*)d_in[3];   // [H,3H]
  const float* b_attn = (const float*)d_in[4];   // [H]
  const float* vv     = (const float*)d_in[5];   // [H]
  const float* W_cov  = (const float*)d_in[6];   // [H,1]
  float* out = (float*)d_out;

  u16* W2bf = (u16*)d_ws;                              // 512 KB (fragment-major)
  float* r  = (float*)((char*)d_ws + 512 * 1024);      // 64 KB
  float* u  = r + 32 * 512;                            // 2 KB
  float* part = u + 512;                               // 32*2048*4 = 256 KB (final scores)

  hipLaunchKernelGGL(prep_kernel, dim3(256), dim3(256), 0, stream,
                     hidden, W_attn, b_attn, W_cov, W2bf, r, u);
  hipLaunchKernelGGL(gemm_score, dim3(1024), dim3(1024), 0, stream,
                     enc, W2bf, r, u, vv, cov, part);
  hipLaunchKernelGGL(softmax_kernel, dim3(32), dim3(256), 0, stream,
                     part, cov, out);
}